// Round 4
// baseline (542.380 us; speedup 1.0000x reference)
//
#include <hip/hip_runtime.h>
#include <hip/hip_cooperative_groups.h>

namespace cg = cooperative_groups;

#define B_SZ 4
#define T_TXT 2048
#define DIM 2048
#define T_IMG 8
#define N_LAT 64
#define DIM_VIS 1024
#define HEADS 16
#define DIM_HEAD 64
#define INNER 1024
#define T_MED (T_IMG * N_LAT)   /* 512 */
#define KV_N (2 * INNER)        /* 2048 */

typedef _Float16 half8  __attribute__((ext_vector_type(8)));
typedef float    f32x4  __attribute__((ext_vector_type(4)));

#define AS1 __attribute__((address_space(1)))
#define AS3 __attribute__((address_space(3)))

__device__ __forceinline__ void load_lds16(const _Float16* g, _Float16* l)
{
    // async global->LDS DMA, 16B per lane; LDS dest = wave-uniform base + lane*16
    __builtin_amdgcn_global_load_lds((const AS1 void*)g, (AS3 void*)l, 16, 0, 0);
}

#define GBAR()   do { asm volatile("" ::: "memory"); __builtin_amdgcn_s_barrier(); \
                      asm volatile("" ::: "memory"); } while (0)
#define GLGKM0() do { asm volatile("s_waitcnt lgkmcnt(0)" ::: "memory"); \
                      __builtin_amdgcn_sched_barrier(0); } while (0)
#define GVM(n)   asm volatile("s_waitcnt vmcnt(" #n ")" ::: "memory")

// ---------------------------------------------------------------------------
// Cooperative megakernel: 256 blocks x 512 threads, 1 block/CU (128 KB LDS).
// Stage 0: prepass (LN + media->f16 + 3 weight transposes), 15360 tasks
// Stage 1: KV 128^2 GEMM (256 uniform tasks) then Q 256x128 GEMM (256 tasks)
// Stage 2: masked attention (512 tasks, 2 per block via sub-split)
// Stage 3: O-projection 256^2 8-phase GEMM (256 tasks)
// grid.sync() between cross-block-dependent stages.
// ---------------------------------------------------------------------------
__global__ __launch_bounds__(512, 2)
void mega(const float* __restrict__ x, const float* __restrict__ media,
          const float* __restrict__ norm_w, const float* __restrict__ norm_b,
          const float* __restrict__ Wq, const float* __restrict__ Wkv,
          const float* __restrict__ Wo,
          _Float16* __restrict__ xn, _Float16* __restrict__ qbuf,
          _Float16* __restrict__ kvb, _Float16* __restrict__ woT,
          _Float16* __restrict__ wqT, _Float16* __restrict__ wkvT,
          _Float16* __restrict__ mediaf, _Float16* __restrict__ attnb,
          float* __restrict__ out)
{
    __shared__ __align__(16) char SMEM[131072];
    cg::grid_group grid = cg::this_grid();

    const int tid  = threadIdx.x;
    const int lane = tid & 63;
    const int wave = tid >> 6;
    const int c15  = lane & 15;
    const int g    = lane >> 4;

    // ======================= Stage 0: prepass ===========================
    {
        const int sub = tid >> 8;            // 0/1: two 256-thread sub-blocks
        const int t   = tid & 255;
        float* red = (float*)SMEM;                                  // [2][8]
        float (*tile)[33] = (float(*)[33])(SMEM + 64 + sub * (32 * 33 * 4));

        for (int it = 0; it < 30; ++it) {
            const int task = it * 512 + blockIdx.x * 2 + sub;
            if (task < 8192) {
                // ---- LayerNorm row (A: reduce; sync; B: normalize+store)
                const float* xr = x + (long)task * DIM;
                const int base = t * 8;
                const float4 a = *(const float4*)(xr + base);
                const float4 c = *(const float4*)(xr + base + 4);
                float s  = a.x + a.y + a.z + a.w + c.x + c.y + c.z + c.w;
                float sq = a.x*a.x + a.y*a.y + a.z*a.z + a.w*a.w
                         + c.x*c.x + c.y*c.y + c.z*c.z + c.w*c.w;
#pragma unroll
                for (int off = 32; off; off >>= 1) {
                    s  += __shfl_xor(s, off);
                    sq += __shfl_xor(sq, off);
                }
                const int wv = t >> 6;
                if ((t & 63) == 0) { red[sub*8 + wv] = s; red[sub*8 + 4 + wv] = sq; }
                __syncthreads();
                s  = red[sub*8+0] + red[sub*8+1] + red[sub*8+2] + red[sub*8+3];
                sq = red[sub*8+4] + red[sub*8+5] + red[sub*8+6] + red[sub*8+7];
                const float mean = s * (1.0f / DIM);
                const float var  = sq * (1.0f / DIM) - mean * mean;
                const float rstd = rsqrtf(var + 1e-5f);
                const float4 w0 = *(const float4*)(norm_w + base);
                const float4 w1 = *(const float4*)(norm_w + base + 4);
                const float4 b0 = *(const float4*)(norm_b + base);
                const float4 b1 = *(const float4*)(norm_b + base + 4);
                half8 o;
                o[0] = (_Float16)((a.x - mean) * rstd * w0.x + b0.x);
                o[1] = (_Float16)((a.y - mean) * rstd * w0.y + b0.y);
                o[2] = (_Float16)((a.z - mean) * rstd * w0.z + b0.z);
                o[3] = (_Float16)((a.w - mean) * rstd * w0.w + b0.w);
                o[4] = (_Float16)((c.x - mean) * rstd * w1.x + b1.x);
                o[5] = (_Float16)((c.y - mean) * rstd * w1.y + b1.y);
                o[6] = (_Float16)((c.z - mean) * rstd * w1.z + b1.z);
                o[7] = (_Float16)((c.w - mean) * rstd * w1.w + b1.w);
                *(half8*)(xn + (long)task * DIM + base) = o;
                __syncthreads();
            } else if (task < 9216) {
                // ---- media fp32 -> f16
                const long i = ((long)(task - 8192) * 256 + t) * 8;
                const float4 a = *(const float4*)(media + i);
                const float4 c = *(const float4*)(media + i + 4);
                half8 o;
                o[0] = (_Float16)a.x; o[1] = (_Float16)a.y; o[2] = (_Float16)a.z; o[3] = (_Float16)a.w;
                o[4] = (_Float16)c.x; o[5] = (_Float16)c.y; o[6] = (_Float16)c.z; o[7] = (_Float16)c.w;
                __syncthreads();
                *(half8*)(mediaf + i) = o;
                __syncthreads();
            } else if (task < 11264) {
                // ---- Wkv [1024][2048] -> wkvT [2048][1024]
                const int id = task - 9216;
                const int n0 = (id & 63) * 32, k0 = (id >> 6) * 32;
                const int tx = t & 31, ty = t >> 5;
#pragma unroll
                for (int i = 0; i < 32; i += 8)
                    tile[ty + i][tx] = Wkv[(long)(k0 + ty + i) * KV_N + n0 + tx];
                __syncthreads();
#pragma unroll
                for (int i = 0; i < 32; i += 8)
                    wkvT[(long)(n0 + ty + i) * DIM_VIS + k0 + tx] = (_Float16)tile[tx][ty + i];
                __syncthreads();
            } else if (task < 13312) {
                // ---- Wq [2048][1024] -> wqT [1024][2048]
                const int id = task - 11264;
                const int n0 = (id & 31) * 32, k0 = (id >> 5) * 32;
                const int tx = t & 31, ty = t >> 5;
#pragma unroll
                for (int i = 0; i < 32; i += 8)
                    tile[ty + i][tx] = Wq[(long)(k0 + ty + i) * INNER + n0 + tx];
                __syncthreads();
#pragma unroll
                for (int i = 0; i < 32; i += 8)
                    wqT[(long)(n0 + ty + i) * DIM + k0 + tx] = (_Float16)tile[tx][ty + i];
                __syncthreads();
            } else {
                // ---- Wo [1024][2048] -> woT [2048][1024]
                const int id = task - 13312;
                const int n0 = (id & 63) * 32, k0 = (id >> 6) * 32;
                const int tx = t & 31, ty = t >> 5;
#pragma unroll
                for (int i = 0; i < 32; i += 8)
                    tile[ty + i][tx] = Wo[(long)(k0 + ty + i) * DIM + n0 + tx];
                __syncthreads();
#pragma unroll
                for (int i = 0; i < 32; i += 8)
                    woT[(long)(n0 + ty + i) * INNER + k0 + tx] = (_Float16)tile[tx][ty + i];
                __syncthreads();
            }
        }
    }

    __threadfence();
    grid.sync();

    // =========== Stage 1a: KV GEMM, 128x128 tile, 3-buffer depth-2 =======
    // kvb[2048][2048] = mediaf[2048][1024] @ wkvT[2048][1024]^T
    {
        const int L = blockIdx.x;                   // 16x16 grid, XCD remap
        const int xcd = L & 7, t2 = L >> 3;
        const int by = xcd * 2 + (t2 & 1);          // bandsPer = 2
        const int bx = t2 >> 1;
        const int m0 = by * 128, n0 = bx * 128;

        _Float16* Ab = (_Float16*)SMEM;             // 3 x 128x64 = 48 KB
        _Float16* Bb = (_Float16*)(SMEM + 49152);   // 3 x 128x64 = 48 KB

        const int srow8 = wave * 8 + (lane >> 3);   // 0..63
        const int sslot = lane & 7;
        const int wmk = wave >> 1;                  // 0..3: 32 rows each
        const int wnk = wave & 1;                   // 0..1: 64 cols each

        auto STK = [&](const int tt) {
            const int bi = tt % 3;
#pragma unroll
            for (int rb = 0; rb < 2; ++rb) {
                const int row = rb * 64 + srow8;
                load_lds16(mediaf + (long)(m0 + row) * DIM_VIS + tt * 64 + ((sslot ^ (row & 7)) << 3),
                           Ab + bi * 8192 + (rb * 64 + wave * 8) * 64);
                load_lds16(wkvT + (long)(n0 + row) * DIM_VIS + tt * 64 + ((sslot ^ (row & 7)) << 3),
                           Bb + bi * 8192 + (rb * 64 + wave * 8) * 64);
            }
        };

        half8 afk[2][2], bfk[4][2];
        f32x4 acck[2][4] = {};

        // prologue: tiles 0,1 staged; vmcnt(4) -> tile0 landed (tile1 in flight)
        STK(0); STK(1);
        GVM(4);
        GBAR();

        const int nt = DIM_VIS / 64;                // 16 K-tiles
        for (int t = 0; t < nt; ++t) {
            const int bi = t % 3;
#pragma unroll
            for (int i = 0; i < 2; ++i) {
                const int row = wmk * 32 + i * 16 + c15;
#pragma unroll
                for (int s = 0; s < 2; ++s)
                    afk[i][s] = *(const half8*)&Ab[bi * 8192 + row * 64 + (((s * 4 + g) ^ (row & 7)) << 3)];
            }
#pragma unroll
            for (int tj = 0; tj < 4; ++tj) {
                const int row = wnk * 64 + tj * 16 + c15;
#pragma unroll
                for (int s = 0; s < 2; ++s)
                    bfk[tj][s] = *(const half8*)&Bb[bi * 8192 + row * 64 + (((s * 4 + g) ^ (row & 7)) << 3)];
            }
            if (t + 2 < nt) STK(t + 2);
            GBAR(); GLGKM0();
            __builtin_amdgcn_s_setprio(1);
#pragma unroll
            for (int tj = 0; tj < 4; ++tj)
#pragma unroll
                for (int i = 0; i < 2; ++i) {
                    acck[i][tj] = __builtin_amdgcn_mfma_f32_16x16x32_f16(afk[i][0], bfk[tj][0], acck[i][tj], 0, 0, 0);
                    acck[i][tj] = __builtin_amdgcn_mfma_f32_16x16x32_f16(afk[i][1], bfk[tj][1], acck[i][tj], 0, 0, 0);
                }
            __builtin_amdgcn_s_setprio(0);
            if (t + 2 < nt) { GVM(4); } else if (t + 1 < nt) { GVM(0); }
            GBAR();
        }

        const int colb = n0 + wnk * 64 + c15;
        const int rowb = m0 + wmk * 32 + g * 4;
#pragma unroll
        for (int i = 0; i < 2; ++i)
#pragma unroll
            for (int tj = 0; tj < 4; ++tj)
#pragma unroll
                for (int r = 0; r < 4; ++r)
                    kvb[(long)(rowb + i * 16 + r) * KV_N + colb + tj * 16] = (_Float16)acck[i][tj][r];
    }

    GBAR();   // LDS reuse boundary (all frag reads drained above)

    // =========== Stage 1b: Q GEMM, 256x128 tile (proven n128 schedule) ====
    // qbuf[8192][1024] = xn[8192][2048] @ wqT[1024][2048]^T
    {
        const int L = blockIdx.x;                   // 8x32 grid, XCD remap
        const int xcd = L & 7, t2 = L >> 3;
        const int by = xcd * 4 + (t2 & 3);          // bandsPer = 4
        const int bx = t2 >> 2;
        const int m0 = by * 256, n0 = bx * 128;
        const int Kq = DIM;                          // 2048

        _Float16* As = (_Float16*)SMEM;             // 2 x 256x64 = 64 KB
        _Float16* Bs = (_Float16*)(SMEM + 65536);   // 2 x 128x64 = 32 KB

        const int wm = wave >> 1, wn = wave & 1;
        const int srow8 = wave * 8 + (lane >> 3);
        const int sslot = lane & 7;

        auto STAGE_A = [&](const int tt, const int rb) {
            const int row = rb * 64 + srow8;
            load_lds16(xn + (long)(m0 + row) * Kq + tt * 64 + ((sslot ^ (row & 7)) << 3),
                       As + (tt & 1) * (256 * 64) + (rb * 64 + wave * 8) * 64);
        };
        auto STAGE_B = [&](const int tt, const int rb) {
            const int row = rb * 64 + srow8;
            load_lds16(wqT + (long)(n0 + row) * Kq + tt * 64 + ((sslot ^ (row & 7)) << 3),
                       Bs + (tt & 1) * (128 * 64) + (rb * 64 + wave * 8) * 64);
        };

        half8 af[2][2], bf[4][2];
        f32x4 acc[4][4] = {};

        auto LDA = [&](const int buf, const int h) {
#pragma unroll
            for (int i = 0; i < 2; ++i) {
                const int row = wm * 64 + (h * 2 + i) * 16 + c15;
#pragma unroll
                for (int s = 0; s < 2; ++s)
                    af[i][s] = *(const half8*)&As[buf * (256 * 64) + row * 64 + (((s * 4 + g) ^ (row & 7)) << 3)];
            }
        };
        auto LDB = [&](const int buf) {
#pragma unroll
            for (int tj = 0; tj < 4; ++tj) {
                const int row = wn * 64 + tj * 16 + c15;
#pragma unroll
                for (int s = 0; s < 2; ++s)
                    bf[tj][s] = *(const half8*)&Bs[buf * (128 * 64) + row * 64 + (((s * 4 + g) ^ (row & 7)) << 3)];
            }
        };
        auto MMA = [&](f32x4 (&a0)[4], f32x4 (&a1)[4]) {
            __builtin_amdgcn_s_setprio(1);
#pragma unroll
            for (int tj = 0; tj < 4; ++tj) {
                a0[tj] = __builtin_amdgcn_mfma_f32_16x16x32_f16(af[0][0], bf[tj][0], a0[tj], 0, 0, 0);
                a0[tj] = __builtin_amdgcn_mfma_f32_16x16x32_f16(af[0][1], bf[tj][1], a0[tj], 0, 0, 0);
                a1[tj] = __builtin_amdgcn_mfma_f32_16x16x32_f16(af[1][0], bf[tj][0], a1[tj], 0, 0, 0);
                a1[tj] = __builtin_amdgcn_mfma_f32_16x16x32_f16(af[1][1], bf[tj][1], a1[tj], 0, 0, 0);
            }
            __builtin_amdgcn_s_setprio(0);
        };

        STAGE_A(0, 0); STAGE_A(0, 1); STAGE_A(0, 2); STAGE_A(0, 3);
        STAGE_B(0, 0); STAGE_B(0, 1);
        STAGE_B(1, 0); STAGE_B(1, 1);
        GVM(2);
        GBAR();

        const int np = Kq >> 7;                     // 16 pairs
        for (int p = 0; p < np; ++p) {
            const int t = 2 * p;
            const bool s2 = (p + 1 < np);

            LDA(0, 0); LDB(0);
            STAGE_A(t + 1, 0); STAGE_A(t + 1, 1); STAGE_A(t + 1, 2); STAGE_A(t + 1, 3);
            GBAR(); GLGKM0();
            MMA(acc[0], acc[1]);
            GBAR();
            LDA(0, 1);
            if (s2) { STAGE_B(t + 2, 0); STAGE_B(t + 2, 1); }
            GBAR(); GLGKM0();
            MMA(acc[2], acc[3]);
            if (s2) { GVM(2); } else { GVM(0); }
            GBAR();
            LDA(1, 0); LDB(1);
            if (s2) { STAGE_A(t + 2, 0); STAGE_A(t + 2, 1); STAGE_A(t + 2, 2); STAGE_A(t + 2, 3); }
            GBAR(); GLGKM0();
            MMA(acc[0], acc[1]);
            GBAR();
            LDA(1, 1);
            if (s2) { STAGE_B(t + 3, 0); STAGE_B(t + 3, 1); }
            GBAR(); GLGKM0();
            MMA(acc[2], acc[3]);
            if (s2) { GVM(2); }
            GBAR();
        }

        const int colb = n0 + wn * 64 + c15;
        const int rowb = m0 + wm * 64 + g * 4;
#pragma unroll
        for (int ti = 0; ti < 4; ++ti)
#pragma unroll
            for (int tj = 0; tj < 4; ++tj)
#pragma unroll
                for (int r = 0; r < 4; ++r)
                    qbuf[(long)(rowb + ti * 16 + r) * INNER + colb + tj * 16] = (_Float16)acc[ti][tj][r];
    }

    __threadfence();
    grid.sync();

    // ================= Stage 2: masked attention (512 tasks) =============
    {
        constexpr int LP = 72;
        const int sub = tid >> 8;
        const int t   = tid & 255;
        const int ln  = t & 63;
        const int w   = t >> 6;
        const int cc  = ln & 15;
        const int gg  = ln >> 4;

        const int a  = blockIdx.x * 2 + sub;        // 0..511
        const int b  = a >> 7;
        const int h  = (a >> 3) & 15;
        const int s  = a & 7;

        char* base = SMEM + sub * 55296;
        _Float16* Ks = (_Float16*)base;             // 64*72*2 = 9216 B
        _Float16* Vt = (_Float16*)(base + 9216);    // 9216 B
        _Float16* Ps = (_Float16*)(base + 18432);   // 4*64*72*2 = 36864 B

        const long kvbase = ((long)(b * T_MED + s * N_LAT)) * KV_N + h * DIM_HEAD;

#pragma unroll
        for (int it = 0; it < 2; ++it) {
            const int id = it * 256 + t;
            const int key = id >> 3, c = id & 7;
            *(half8*)&Ks[key * LP + c * 8] =
                *(const half8*)(kvb + kvbase + (long)key * KV_N + c * 8);
        }
#pragma unroll
        for (int it = 0; it < 2; ++it) {
            const int id = it * 256 + t;
            const int key = id >> 3, c = id & 7;
            const half8 v = *(const half8*)(kvb + kvbase + INNER + (long)key * KV_N + c * 8);
#pragma unroll
            for (int j = 0; j < 8; ++j)
                Vt[(c * 8 + j) * LP + key] = v[j];
        }
        __syncthreads();

        const long q0 = ((long)(b * T_TXT + s * 256 + w * 64)) * INNER + h * DIM_HEAD;
        half8 qf[4][2];
#pragma unroll
        for (int tm = 0; tm < 4; ++tm)
#pragma unroll
            for (int ks = 0; ks < 2; ++ks)
                qf[tm][ks] = *(const half8*)(qbuf + q0 + (long)(tm * 16 + cc) * INNER + ks * 32 + gg * 8);

        f32x4 acc[4][4] = {};
#pragma unroll
        for (int tn = 0; tn < 4; ++tn) {
            const half8 kf0 = *(const half8*)&Ks[(tn * 16 + cc) * LP + gg * 8];
            const half8 kf1 = *(const half8*)&Ks[(tn * 16 + cc) * LP + 32 + gg * 8];
#pragma unroll
            for (int tm = 0; tm < 4; ++tm) {
                acc[tm][tn] = __builtin_amdgcn_mfma_f32_16x16x32_f16(qf[tm][0], kf0, acc[tm][tn], 0, 0, 0);
                acc[tm][tn] = __builtin_amdgcn_mfma_f32_16x16x32_f16(qf[tm][1], kf1, acc[tm][tn], 0, 0, 0);
            }
        }

        constexpr float sc = 0.125f;
        _Float16* Pw = Ps + w * (64 * LP);
#pragma unroll
        for (int tm = 0; tm < 4; ++tm)
#pragma unroll
            for (int r = 0; r < 4; ++r) {
                float m = fmaxf(fmaxf(acc[tm][0][r], acc[tm][1][r]),
                                fmaxf(acc[tm][2][r], acc[tm][3][r]));
#pragma unroll
                for (int off = 1; off < 16; off <<= 1) m = fmaxf(m, __shfl_xor(m, off));
                float e0 = __expf((acc[tm][0][r] - m) * sc);
                float e1 = __expf((acc[tm][1][r] - m) * sc);
                float e2 = __expf((acc[tm][2][r] - m) * sc);
                float e3 = __expf((acc[tm][3][r] - m) * sc);
                float sum = e0 + e1 + e2 + e3;
#pragma unroll
                for (int off = 1; off < 16; off <<= 1) sum += __shfl_xor(sum, off);
                const float inv = 1.0f / sum;
                const int row = tm * 16 + gg * 4 + r;
                Pw[row * LP +  0 + cc] = (_Float16)(e0 * inv);
                Pw[row * LP + 16 + cc] = (_Float16)(e1 * inv);
                Pw[row * LP + 32 + cc] = (_Float16)(e2 * inv);
                Pw[row * LP + 48 + cc] = (_Float16)(e3 * inv);
            }
        __syncthreads();

        f32x4 o[4][4] = {};
#pragma unroll
        for (int ks = 0; ks < 2; ++ks) {
            half8 pf[4];
#pragma unroll
            for (int tm = 0; tm < 4; ++tm)
                pf[tm] = *(const half8*)&Pw[(tm * 16 + cc) * LP + ks * 32 + gg * 8];
#pragma unroll
            for (int tn = 0; tn < 4; ++tn) {
                const half8 vf = *(const half8*)&Vt[(tn * 16 + cc) * LP + ks * 32 + gg * 8];
#pragma unroll
                for (int tm = 0; tm < 4; ++tm)
                    o[tm][tn] = __builtin_amdgcn_mfma_f32_16x16x32_f16(pf[tm], vf, o[tm][tn], 0, 0, 0);
            }
        }

        const long obase = ((long)(b * T_TXT + s * 256 + w * 64)) * INNER + h * DIM_HEAD;
#pragma unroll
        for (int tm = 0; tm < 4; ++tm)
#pragma unroll
            for (int tn = 0; tn < 4; ++tn)
#pragma unroll
                for (int r = 0; r < 4; ++r)
                    attnb[obase + (long)(tm * 16 + gg * 4 + r) * INNER + tn * 16 + cc] =
                        (_Float16)o[tm][tn][r];
    }

    __threadfence();
    grid.sync();

    // ============== Stage 3: O-projection, 256^2 8-phase GEMM ============
    // out[8192][2048] (fp32) = attnb[8192][1024] @ woT[2048][1024]^T
    {
        const int L = blockIdx.x;                   // 8x32 grid, XCD remap
        const int xcd = L & 7, t2 = L >> 3;
        const int by = xcd * 4 + (t2 & 3);          // bandsPer = 4
        const int bx = t2 >> 2;
        const int m0 = by * 256, n0 = bx * 256;
        const int Ko = INNER;                        // 1024

        _Float16* As = (_Float16*)SMEM;             // 2 x 256x64 = 64 KB
        _Float16* Bs = (_Float16*)(SMEM + 65536);   // 2 x 256x64 = 64 KB

        const int wm = wave >> 2, wn = wave & 3;
        const int srow8 = wave * 8 + (lane >> 3);
        const int sslot = lane & 7;

        auto STAGE_A = [&](const int tt, const int rb) {
            const int row = rb * 64 + srow8;
            load_lds16(attnb + (long)(m0 + row) * Ko + tt * 64 + ((sslot ^ (row & 7)) << 3),
                       As + (tt & 1) * (256 * 64) + (rb * 64 + wave * 8) * 64);
        };
        auto STAGE_B = [&](const int tt, const int rb) {
            const int row = rb * 64 + srow8;
            load_lds16(woT + (long)(n0 + row) * Ko + tt * 64 + ((sslot ^ (row & 7)) << 3),
                       Bs + (tt & 1) * (256 * 64) + (rb * 64 + wave * 8) * 64);
        };

        half8 af[4][2], bf0[2][2], bf1[2][2];
        f32x4 acc[2][2][4][2] = {};

        auto LDA = [&](const int buf, const int sm) {
#pragma unroll
            for (int ti = 0; ti < 4; ++ti) {
                const int row = sm * 128 + wm * 64 + ti * 16 + c15;
#pragma unroll
                for (int s = 0; s < 2; ++s)
                    af[ti][s] = *(const half8*)&As[buf * (256 * 64) + row * 64 + (((s * 4 + g) ^ (row & 7)) << 3)];
            }
        };
        auto LDB = [&](const int buf, const int sn, half8 (&bf)[2][2]) {
#pragma unroll
            for (int tj = 0; tj < 2; ++tj) {
                const int row = sn * 128 + wn * 32 + tj * 16 + c15;
#pragma unroll
                for (int s = 0; s < 2; ++s)
                    bf[tj][s] = *(const half8*)&Bs[buf * (256 * 64) + row * 64 + (((s * 4 + g) ^ (row & 7)) << 3)];
            }
        };
        auto MMA = [&](f32x4 (&aq)[4][2], const half8 (&bf)[2][2]) {
            __builtin_amdgcn_s_setprio(1);
#pragma unroll
            for (int ti = 0; ti < 4; ++ti)
#pragma unroll
                for (int tj = 0; tj < 2; ++tj) {
                    aq[ti][tj] = __builtin_amdgcn_mfma_f32_16x16x32_f16(
                        af[ti][0], bf[tj][0], aq[ti][tj], 0, 0, 0);
                    aq[ti][tj] = __builtin_amdgcn_mfma_f32_16x16x32_f16(
                        af[ti][1], bf[tj][1], aq[ti][tj], 0, 0, 0);
                }
            __builtin_amdgcn_s_setprio(0);
        };

        STAGE_A(0, 0); STAGE_A(0, 1); STAGE_A(0, 2); STAGE_A(0, 3);
        STAGE_B(0, 0); STAGE_B(0, 1); STAGE_B(0, 2); STAGE_B(0, 3);
        STAGE_A(1, 0); STAGE_A(1, 1);
        STAGE_B(1, 0); STAGE_B(1, 1); STAGE_B(1, 2); STAGE_B(1, 3);
        GVM(6);
        GBAR();

        const int npairs = Ko >> 7;                 // 8 pairs
        for (int p = 0; p < npairs; ++p) {
            const int t = 2 * p;
            const bool full = (p + 1 < npairs);

            LDA(0, 0); LDB(0, 0, bf0);
            STAGE_A(t + 1, 2); STAGE_A(t + 1, 3);
            GBAR(); GLGKM0();
            MMA(acc[0][0], bf0);
            GBAR();
            LDB(0, 1, bf1);
            if (full) { STAGE_A(t + 2, 0); STAGE_A(t + 2, 1); }
            GBAR(); GLGKM0();
            MMA(acc[0][1], bf1);
            GBAR();
            LDA(0, 1);
            if (full) { STAGE_B(t + 2, 0); STAGE_B(t + 2, 1); }
            GBAR(); GLGKM0();
            MMA(acc[1][1], bf1);
            GBAR();
            if (full) { STAGE_B(t + 2, 2); STAGE_B(t + 2, 3); }
            GBAR();
            MMA(acc[1][0], bf0);
            if (full) { GVM(6); } else { GVM(0); }
            GBAR();
            LDA(1, 0); LDB(1, 0, bf0);
            if (full) { STAGE_A(t + 2, 2); STAGE_A(t + 2, 3); }
            GBAR(); GLGKM0();
            MMA(acc[0][0], bf0);
            GBAR();
            LDB(1, 1, bf1);
            if (full) { STAGE_A(t + 3, 0); STAGE_A(t + 3, 1); }
            GBAR(); GLGKM0();
            MMA(acc[0][1], bf1);
            GBAR();
            LDA(1, 1);
            if (full) { STAGE_B(t + 3, 0); STAGE_B(t + 3, 1); }
            GBAR(); GLGKM0();
            MMA(acc[1][1], bf1);
            GBAR();
            if (full) { STAGE_B(t + 3, 2); STAGE_B(t + 3, 3); }
            GBAR();
            MMA(acc[1][0], bf0);
            if (full) { GVM(6); }
            GBAR();
        }

        const int colb = n0 + wn * 32 + c15;
        const int rowb = m0 + wm * 64 + g * 4;
#pragma unroll
        for (int sm = 0; sm < 2; ++sm)
#pragma unroll
            for (int sn = 0; sn < 2; ++sn)
#pragma unroll
                for (int ti = 0; ti < 4; ++ti)
#pragma unroll
                    for (int tj = 0; tj < 2; ++tj)
#pragma unroll
                        for (int r = 0; r < 4; ++r) {
                            const long idx = (long)(rowb + sm * 128 + ti * 16 + r) * DIM
                                           + colb + sn * 128 + tj * 16;
                            out[idx] = acc[sm][sn][ti][tj][r];
                        }
    }
}

// ---------------------------------------------------------------------------
extern "C" void kernel_launch(void* const* d_in, const int* in_sizes, int n_in,
                              void* d_out, int out_size, void* d_ws, size_t ws_size,
                              hipStream_t stream)
{
    (void)in_sizes; (void)n_in; (void)out_size; (void)ws_size;
    const float* x      = (const float*)d_in[0];
    const float* media  = (const float*)d_in[1];
    const float* norm_w = (const float*)d_in[2];
    const float* norm_b = (const float*)d_in[3];
    const float* Wq     = (const float*)d_in[4];
    const float* Wkv    = (const float*)d_in[5];
    const float* Wo     = (const float*)d_in[6];

    char* ws = (char*)d_ws;
    char* outc = (char*)d_out;
    // ws (60 MB):
    _Float16* xn     = (_Float16*)ws;                    // [0,32) MB
    _Float16* attnb  = (_Float16*)ws;                    // [0,16) MB alias (xn dead after Q)
    _Float16* qbuf   = (_Float16*)(ws + (32ull << 20));  // [32,48) MB
    _Float16* kvb    = (_Float16*)(ws + (48ull << 20));  // [48,56) MB
    _Float16* woT    = (_Float16*)(ws + (56ull << 20));  // [56,60) MB
    // d_out scratch (dead before stage 3, which overwrites all of d_out):
    _Float16* wqT    = (_Float16*)outc;                  // [0,4) MB
    _Float16* wkvT   = (_Float16*)(outc + (4ull << 20)); // [4,8) MB
    _Float16* mediaf = (_Float16*)(outc + (8ull << 20)); // [8,12) MB
    float* out = (float*)d_out;

    void* args[] = { (void*)&x, (void*)&media, (void*)&norm_w, (void*)&norm_b,
                     (void*)&Wq, (void*)&Wkv, (void*)&Wo,
                     (void*)&xn, (void*)&qbuf, (void*)&kvb, (void*)&woT,
                     (void*)&wqT, (void*)&wkvT, (void*)&mediaf, (void*)&attnb,
                     (void*)&out };
    hipLaunchCooperativeKernel((const void*)mega, dim3(256), dim3(512),
                               args, 0, stream);
}

// Round 5
// 256.711 us; speedup vs baseline: 2.1128x; 2.1128x over previous
//
#include <hip/hip_runtime.h>
#include <hip/hip_bf16.h>

#define B_SZ 4
#define T_TXT 2048
#define DIM 2048
#define T_IMG 8
#define N_LAT 64
#define DIM_VIS 1024
#define HEADS 16
#define DIM_HEAD 64
#define INNER 1024
#define T_MED (T_IMG * N_LAT)   /* 512 */
#define KV_N (2 * INNER)        /* 2048 */

typedef _Float16 half8  __attribute__((ext_vector_type(8)));
typedef float    f32x4  __attribute__((ext_vector_type(4)));

#define AS1 __attribute__((address_space(1)))
#define AS3 __attribute__((address_space(3)))

__device__ __forceinline__ void load_lds16(const _Float16* g, _Float16* l)
{
    // async global->LDS DMA, 16B per lane; LDS dest = wave-uniform base + lane*16
    __builtin_amdgcn_global_load_lds((const AS1 void*)g, (AS3 void*)l, 16, 0, 0);
}

#define GBAR()   do { asm volatile("" ::: "memory"); __builtin_amdgcn_s_barrier(); \
                      asm volatile("" ::: "memory"); } while (0)
#define GLGKM0() do { asm volatile("s_waitcnt lgkmcnt(0)" ::: "memory"); \
                      __builtin_amdgcn_sched_barrier(0); } while (0)
#define GVM(n)   asm volatile("s_waitcnt vmcnt(" #n ")" ::: "memory")

// ---------------------------------------------------------------------------
// Fused prepass, 5 independent segments in one dispatch (10752 blocks):
//   [0, 8192)      LayerNorm rows -> xn f16
//   [8192, 9216)   media fp32 -> f16                       (scratch in d_out)
//   [9216, 9728)   Wkv [1024][2048] -> wkvT [2048][1024]   (scratch in d_out)
//   [9728, 10240)  Wq  [2048][1024] -> wqT  [1024][2048]   (scratch in d_out)
//   [10240, 10752) Wo  [1024][2048] -> woT  [2048][1024]   (ws)
// Transposes use 64x64 tiles (16 els/thread).  d_out scratch is safe: it is
// consumed by the QKV dispatch and d_out is only written by the final O-GEMM.
// ---------------------------------------------------------------------------
__global__ __launch_bounds__(256)
void prepass(const float* __restrict__ x, const float* __restrict__ gw,
             const float* __restrict__ gb, _Float16* __restrict__ xn,
             const float* __restrict__ media, _Float16* __restrict__ mediaf,
             const float* __restrict__ Wkv, _Float16* __restrict__ wkvT,
             const float* __restrict__ Wq, _Float16* __restrict__ wqT,
             const float* __restrict__ Wo, _Float16* __restrict__ woT)
{
    __shared__ float red[8];
    __shared__ float tile[64][65];
    const int bid = blockIdx.x;
    const int t = threadIdx.x;

    if (bid < 8192) {
        // ---- LayerNorm row
        const long row = bid;
        const float* xr = x + row * DIM;
        const int base = t * 8;
        const float4 a = *(const float4*)(xr + base);
        const float4 c = *(const float4*)(xr + base + 4);
        float s  = a.x + a.y + a.z + a.w + c.x + c.y + c.z + c.w;
        float sq = a.x*a.x + a.y*a.y + a.z*a.z + a.w*a.w
                 + c.x*c.x + c.y*c.y + c.z*c.z + c.w*c.w;
#pragma unroll
        for (int off = 32; off; off >>= 1) {
            s  += __shfl_xor(s, off);
            sq += __shfl_xor(sq, off);
        }
        const int wv = t >> 6, ln = t & 63;
        if (ln == 0) { red[wv] = s; red[4 + wv] = sq; }
        __syncthreads();
        s  = red[0] + red[1] + red[2] + red[3];
        sq = red[4] + red[5] + red[6] + red[7];
        const float mean = s * (1.0f / DIM);
        const float var  = sq * (1.0f / DIM) - mean * mean;
        const float rstd = rsqrtf(var + 1e-5f);
        const float4 w0 = *(const float4*)(gw + base);
        const float4 w1 = *(const float4*)(gw + base + 4);
        const float4 b0 = *(const float4*)(gb + base);
        const float4 b1 = *(const float4*)(gb + base + 4);
        half8 o;
        o[0] = (_Float16)((a.x - mean) * rstd * w0.x + b0.x);
        o[1] = (_Float16)((a.y - mean) * rstd * w0.y + b0.y);
        o[2] = (_Float16)((a.z - mean) * rstd * w0.z + b0.z);
        o[3] = (_Float16)((a.w - mean) * rstd * w0.w + b0.w);
        o[4] = (_Float16)((c.x - mean) * rstd * w1.x + b1.x);
        o[5] = (_Float16)((c.y - mean) * rstd * w1.y + b1.y);
        o[6] = (_Float16)((c.z - mean) * rstd * w1.z + b1.z);
        o[7] = (_Float16)((c.w - mean) * rstd * w1.w + b1.w);
        *(half8*)(xn + row * DIM + base) = o;
    } else if (bid < 9216) {
        // ---- media fp32 -> f16
        const long i = ((long)(bid - 8192) * 256 + t) * 8;
        const float4 a = *(const float4*)(media + i);
        const float4 c = *(const float4*)(media + i + 4);
        half8 o;
        o[0] = (_Float16)a.x; o[1] = (_Float16)a.y; o[2] = (_Float16)a.z; o[3] = (_Float16)a.w;
        o[4] = (_Float16)c.x; o[5] = (_Float16)c.y; o[6] = (_Float16)c.z; o[7] = (_Float16)c.w;
        *(half8*)(mediaf + i) = o;
    } else {
        // ---- 64x64 transpose tiles: in fp32 [K][N] -> out f16 [N][K]
        const float* in; _Float16* out; int N, K, n0, k0;
        if (bid < 9728) {
            const int id = bid - 9216;                 // Wkv: 32 n-tiles x 16 k-tiles
            in = Wkv; out = wkvT; N = KV_N; K = DIM_VIS;
            n0 = (id & 31) * 64; k0 = (id >> 5) * 64;
        } else if (bid < 10240) {
            const int id = bid - 9728;                 // Wq: 16 n-tiles x 32 k-tiles
            in = Wq; out = wqT; N = INNER; K = DIM;
            n0 = (id & 15) * 64; k0 = (id >> 4) * 64;
        } else {
            const int id = bid - 10240;                // Wo: 32 n-tiles x 16 k-tiles
            in = Wo; out = woT; N = DIM; K = INNER;
            n0 = (id & 31) * 64; k0 = (id >> 5) * 64;
        }
        const int tx = t & 63, ty = t >> 6;            // 4 rows per pass
#pragma unroll
        for (int i = 0; i < 64; i += 4)
            tile[i + ty][tx] = in[(long)(k0 + i + ty) * N + n0 + tx];
        __syncthreads();
#pragma unroll
        for (int i = 0; i < 64; i += 4)
            out[(long)(n0 + i + ty) * K + k0 + tx] = (_Float16)tile[tx][i + ty];
    }
}

// ---------------------------------------------------------------------------
// 256x128-tile 8-wave counted-vmcnt GEMM body (f16 C). Schedule per pair:
//   P1: read b0{A0,B}, stage (t+1)A
//   P2: read b0{A1},   stage (t+2)B, GVM(2) -> t+1 landed
//   P3: read b1{A0,B}, stage (t+2)A
//   P4: read b1{A1},   stage (t+3)B, GVM(2) -> t+2 landed
// Outstanding at each gate = 8; GVM(2) keeps the 2 newest (next B).
// Last pair degrades P2's gate to GVM(0); no vmcnt(0) in steady state.
// ---------------------------------------------------------------------------
__device__ __forceinline__
void gemm_n128_body(const _Float16* __restrict__ A, const _Float16* __restrict__ Bt,
                    _Float16* __restrict__ Cp, const int M, const int N, const int K,
                    const int bx, const int by,
                    _Float16* As /*[2][256*64]*/, _Float16* Bs /*[2][128*64]*/)
{
    const int tid  = threadIdx.x;
    const int lane = tid & 63;
    const int wave = tid >> 6;
    const int wm   = wave >> 1;     // 0..3 (m)
    const int wn   = wave & 1;      // 0..1 (n)
    const int c15  = lane & 15;
    const int g    = lane >> 4;

    const int m0 = by * 256, n0 = bx * 128;

    const int srow8 = wave * 8 + (lane >> 3);
    const int sslot = lane & 7;

    auto STAGE_A = [&](const int tt, const int rb) {
        const int row = rb * 64 + srow8;
        load_lds16(A + (long)(m0 + row) * K + tt * 64 + ((sslot ^ (row & 7)) << 3),
                   As + (tt & 1) * (256 * 64) + (rb * 64 + wave * 8) * 64);
    };
    auto STAGE_B = [&](const int tt, const int rb) {
        const int row = rb * 64 + srow8;
        load_lds16(Bt + (long)(n0 + row) * K + tt * 64 + ((sslot ^ (row & 7)) << 3),
                   Bs + (tt & 1) * (128 * 64) + (rb * 64 + wave * 8) * 64);
    };

    half8 af[2][2], bf[4][2];
    f32x4 acc[4][4] = {};

    auto LDA = [&](const int buf, const int h) {
#pragma unroll
        for (int i = 0; i < 2; ++i) {
            const int row = wm * 64 + (h * 2 + i) * 16 + c15;
#pragma unroll
            for (int s = 0; s < 2; ++s)
                af[i][s] = *(const half8*)&As[buf * (256 * 64) + row * 64 + (((s * 4 + g) ^ (row & 7)) << 3)];
        }
    };
    auto LDB = [&](const int buf) {
#pragma unroll
        for (int tj = 0; tj < 4; ++tj) {
            const int row = wn * 64 + tj * 16 + c15;
#pragma unroll
            for (int s = 0; s < 2; ++s)
                bf[tj][s] = *(const half8*)&Bs[buf * (128 * 64) + row * 64 + (((s * 4 + g) ^ (row & 7)) << 3)];
        }
    };
    auto MMA = [&](f32x4 (&a0)[4], f32x4 (&a1)[4]) {
        __builtin_amdgcn_s_setprio(1);
#pragma unroll
        for (int tj = 0; tj < 4; ++tj) {
            a0[tj] = __builtin_amdgcn_mfma_f32_16x16x32_f16(af[0][0], bf[tj][0], a0[tj], 0, 0, 0);
            a0[tj] = __builtin_amdgcn_mfma_f32_16x16x32_f16(af[0][1], bf[tj][1], a0[tj], 0, 0, 0);
            a1[tj] = __builtin_amdgcn_mfma_f32_16x16x32_f16(af[1][0], bf[tj][0], a1[tj], 0, 0, 0);
            a1[tj] = __builtin_amdgcn_mfma_f32_16x16x32_f16(af[1][1], bf[tj][1], a1[tj], 0, 0, 0);
        }
        __builtin_amdgcn_s_setprio(0);
    };

    // prologue: tile0 full (A:4, B:2), tile1 B (2); GVM(2) -> tile0 landed
    STAGE_A(0, 0); STAGE_A(0, 1); STAGE_A(0, 2); STAGE_A(0, 3);
    STAGE_B(0, 0); STAGE_B(0, 1);
    STAGE_B(1, 0); STAGE_B(1, 1);
    GVM(2);
    GBAR();

    const int np = K >> 7;              // pairs of K-tiles
    for (int p = 0; p < np; ++p) {
        const int t = 2 * p;
        const bool s2 = (p + 1 < np);

        // P1: read buf0 A-half0 + B; stage (t+1) A
        LDA(0, 0); LDB(0);
        STAGE_A(t + 1, 0); STAGE_A(t + 1, 1); STAGE_A(t + 1, 2); STAGE_A(t + 1, 3);
        GBAR(); GLGKM0();
        MMA(acc[0], acc[1]);
        GBAR();
        // P2: read buf0 A-half1; stage (t+2) B; gate t+1
        LDA(0, 1);
        if (s2) { STAGE_B(t + 2, 0); STAGE_B(t + 2, 1); }
        GBAR(); GLGKM0();
        MMA(acc[2], acc[3]);
        if (s2) { GVM(2); } else { GVM(0); }
        GBAR();
        // P3: read buf1 A-half0 + B; stage (t+2) A
        LDA(1, 0); LDB(1);
        if (s2) { STAGE_A(t + 2, 0); STAGE_A(t + 2, 1); STAGE_A(t + 2, 2); STAGE_A(t + 2, 3); }
        GBAR(); GLGKM0();
        MMA(acc[0], acc[1]);
        GBAR();
        // P4: read buf1 A-half1; stage (t+3) B; gate t+2
        LDA(1, 1);
        if (s2) { STAGE_B(t + 3, 0); STAGE_B(t + 3, 1); }
        GBAR(); GLGKM0();
        MMA(acc[2], acc[3]);
        if (s2) { GVM(2); }
        GBAR();
    }

    // C write: col = lane&15, row = g*4 + reg
    const int colb = n0 + wn * 64 + c15;
    const int rowb = m0 + wm * 64 + g * 4;
#pragma unroll
    for (int ti = 0; ti < 4; ++ti)
#pragma unroll
        for (int tj = 0; tj < 4; ++tj)
#pragma unroll
            for (int r = 0; r < 4; ++r) {
                const long idx = (long)(rowb + ti * 16 + r) * N + colb + tj * 16;
                Cp[idx] = (_Float16)acc[ti][tj][r];
            }
}

// ---------------------------------------------------------------------------
// Fused KV + Q GEMM dispatch (384 WGs), KV FIRST:
//   blocks [0,128):   kv = media @ WkvT^T  M=2048 N=2048 K=1024 (16x8 grid)
//   blocks [128,384): q  = xn @ WqT^T      M=8192 N=1024 K=2048 (8x32 grid)
// KV-first: short KV tiles retire early so the last 128 Q blocks start at
// ~13us instead of ~44us (1 block/CU).  Both segments 8-aligned and 128===0
// (mod 8), so flat%8 (the HW XCD assignment) is preserved per segment.
// ---------------------------------------------------------------------------
__global__ __launch_bounds__(512, 2)
void gemm_qkv(const _Float16* __restrict__ xn, const _Float16* __restrict__ wqT,
              _Float16* __restrict__ qbuf,
              const _Float16* __restrict__ mediaf, const _Float16* __restrict__ wkvT,
              _Float16* __restrict__ kvb)
{
    __shared__ __align__(16) _Float16 As[2][256 * 64];   // 64 KB
    __shared__ __align__(16) _Float16 Bs[2][128 * 64];   // 32 KB

    const int flat = blockIdx.x;
    const _Float16 *A, *Bt;
    _Float16 *C;
    int M, N, K, mB, L;
    if (flat < 128) { A = mediaf; Bt = wkvT; C = kvb;  M = 2048; N = 2048; K = 1024; mB = 8;  L = flat; }
    else            { A = xn;     Bt = wqT;  C = qbuf; M = 8192; N = 1024; K = 2048; mB = 32; L = flat - 128; }

    int bx, by;
    {
        const int xcd = L & 7, t2 = L >> 3;
        const int bandsPer = mB >> 3;
        by = xcd * bandsPer + (t2 % bandsPer);
        bx = t2 / bandsPer;
    }
    gemm_n128_body(A, Bt, C, M, N, K, bx, by, &As[0][0], &Bs[0][0]);
}

// ---------------------------------------------------------------------------
// 256x256 8-phase GEMM (O-projection, 256 WGs).
// ---------------------------------------------------------------------------
template<bool C_F16>
__global__ __launch_bounds__(512, 2)
void gemm256(const _Float16* __restrict__ A, const _Float16* __restrict__ Bt,
             void* __restrict__ Cp, const int M, const int N, const int K)
{
    __shared__ __align__(16) _Float16 As[2][256 * 64];
    __shared__ __align__(16) _Float16 Bs[2][256 * 64];

    const int tid  = threadIdx.x;
    const int lane = tid & 63;
    const int wave = tid >> 6;
    const int wm   = wave >> 2;
    const int wn   = wave & 3;
    const int c15  = lane & 15;
    const int g    = lane >> 4;

    int bx, by;
    {
        const int nB = gridDim.x, mB = gridDim.y;
        const int L = blockIdx.y * nB + blockIdx.x;
        if ((mB & 7) == 0) {
            const int xcd = L & 7, t2 = L >> 3;
            const int bandsPer = mB >> 3;
            by = xcd * bandsPer + (t2 % bandsPer);
            bx = t2 / bandsPer;
        } else { bx = blockIdx.x; by = blockIdx.y; }
    }
    const int m0 = by * 256, n0 = bx * 256;

    const int srow8 = wave * 8 + (lane >> 3);
    const int sslot = lane & 7;

    auto STAGE_A = [&](const int tt, const int rb) {
        const int row = rb * 64 + srow8;
        load_lds16(A + (long)(m0 + row) * K + tt * 64 + ((sslot ^ (row & 7)) << 3),
                   &As[tt & 1][(rb * 64 + wave * 8) * 64]);
    };
    auto STAGE_B = [&](const int tt, const int rb) {
        const int row = rb * 64 + srow8;
        load_lds16(Bt + (long)(n0 + row) * K + tt * 64 + ((sslot ^ (row & 7)) << 3),
                   &Bs[tt & 1][(rb * 64 + wave * 8) * 64]);
    };

    half8 af[4][2], bf0[2][2], bf1[2][2];
    f32x4 acc[2][2][4][2] = {};

    auto LDA = [&](const int buf, const int sm) {
#pragma unroll
        for (int ti = 0; ti < 4; ++ti) {
            const int row = sm * 128 + wm * 64 + ti * 16 + c15;
#pragma unroll
            for (int s = 0; s < 2; ++s)
                af[ti][s] = *(const half8*)&As[buf][row * 64 + (((s * 4 + g) ^ (row & 7)) << 3)];
        }
    };
    auto LDB = [&](const int buf, const int sn, half8 (&bf)[2][2]) {
#pragma unroll
        for (int tj = 0; tj < 2; ++tj) {
            const int row = sn * 128 + wn * 32 + tj * 16 + c15;
#pragma unroll
            for (int s = 0; s < 2; ++s)
                bf[tj][s] = *(const half8*)&Bs[buf][row * 64 + (((s * 4 + g) ^ (row & 7)) << 3)];
        }
    };
    auto MMA = [&](f32x4 (&aq)[4][2], const half8 (&bf)[2][2]) {
        __builtin_amdgcn_s_setprio(1);
#pragma unroll
        for (int ti = 0; ti < 4; ++ti)
#pragma unroll
            for (int tj = 0; tj < 2; ++tj) {
                aq[ti][tj] = __builtin_amdgcn_mfma_f32_16x16x32_f16(
                    af[ti][0], bf[tj][0], aq[ti][tj], 0, 0, 0);
                aq[ti][tj] = __builtin_amdgcn_mfma_f32_16x16x32_f16(
                    af[ti][1], bf[tj][1], aq[ti][tj], 0, 0, 0);
            }
        __builtin_amdgcn_s_setprio(0);
    };

    STAGE_A(0, 0); STAGE_A(0, 1); STAGE_A(0, 2); STAGE_A(0, 3);
    STAGE_B(0, 0); STAGE_B(0, 1); STAGE_B(0, 2); STAGE_B(0, 3);
    STAGE_A(1, 0); STAGE_A(1, 1);
    STAGE_B(1, 0); STAGE_B(1, 1); STAGE_B(1, 2); STAGE_B(1, 3);
    GVM(6);
    GBAR();

    const int npairs = K >> 7;
    for (int p = 0; p < npairs; ++p) {
        const int t = 2 * p;
        const bool full = (p + 1 < npairs);

        LDA(0, 0); LDB(0, 0, bf0);
        STAGE_A(t + 1, 2); STAGE_A(t + 1, 3);
        GBAR(); GLGKM0();
        MMA(acc[0][0], bf0);
        GBAR();
        LDB(0, 1, bf1);
        if (full) { STAGE_A(t + 2, 0); STAGE_A(t + 2, 1); }
        GBAR(); GLGKM0();
        MMA(acc[0][1], bf1);
        GBAR();
        LDA(0, 1);
        if (full) { STAGE_B(t + 2, 0); STAGE_B(t + 2, 1); }
        GBAR(); GLGKM0();
        MMA(acc[1][1], bf1);
        GBAR();
        if (full) { STAGE_B(t + 2, 2); STAGE_B(t + 2, 3); }
        GBAR();
        MMA(acc[1][0], bf0);
        if (full) { GVM(6); } else { GVM(0); }
        GBAR();
        LDA(1, 0); LDB(1, 0, bf0);
        if (full) { STAGE_A(t + 2, 2); STAGE_A(t + 2, 3); }
        GBAR(); GLGKM0();
        MMA(acc[0][0], bf0);
        GBAR();
        LDB(1, 1, bf1);
        if (full) { STAGE_A(t + 3, 0); STAGE_A(t + 3, 1); }
        GBAR(); GLGKM0();
        MMA(acc[0][1], bf1);
        GBAR();
        LDA(1, 1);
        if (full) { STAGE_B(t + 3, 0); STAGE_B(t + 3, 1); }
        GBAR(); GLGKM0();
        MMA(acc[1][1], bf1);
        GBAR();
        if (full) { STAGE_B(t + 3, 2); STAGE_B(t + 3, 3); }
        GBAR();
        MMA(acc[1][0], bf0);
        if (full) { GVM(6); }
        GBAR();
    }

    const int colb = n0 + wn * 32 + c15;
    const int rowb = m0 + wm * 64 + g * 4;
#pragma unroll
    for (int sm = 0; sm < 2; ++sm)
#pragma unroll
        for (int sn = 0; sn < 2; ++sn)
#pragma unroll
            for (int ti = 0; ti < 4; ++ti)
#pragma unroll
                for (int tj = 0; tj < 2; ++tj)
#pragma unroll
                    for (int r = 0; r < 4; ++r) {
                        const long idx = (long)(rowb + sm * 128 + ti * 16 + r) * N
                                       + colb + sn * 128 + tj * 16;
                        if constexpr (C_F16)
                            ((_Float16*)Cp)[idx] = (_Float16)acc[sm][sn][ti][tj][r];
                        else
                            ((float*)Cp)[idx] = acc[sm][sn][ti][tj][r];
                    }
}

// ---------------------------------------------------------------------------
// MFMA masked cross-attention (unchanged, round-3 proven).
// ---------------------------------------------------------------------------
__global__ __launch_bounds__(256)
void attn_mfma(const _Float16* __restrict__ qg, const _Float16* __restrict__ kv,
               _Float16* __restrict__ attn)
{
    constexpr int LP = 72;
    __shared__ __align__(16) _Float16 Ks[64 * LP];
    __shared__ __align__(16) _Float16 Vt[64 * LP];
    __shared__ __align__(16) _Float16 Ps[4 * 64 * LP];

    const int s = blockIdx.x;
    const int h = blockIdx.y;
    const int b = blockIdx.z;
    const int tid  = threadIdx.x;
    const int lane = tid & 63;
    const int w    = tid >> 6;
    const int c15  = lane & 15;
    const int g    = lane >> 4;

    const long kvbase = ((long)(b * T_MED + s * N_LAT)) * KV_N + h * DIM_HEAD;

#pragma unroll
    for (int it = 0; it < 2; ++it) {
        const int id = it * 256 + tid;
        const int key = id >> 3, c = id & 7;
        *(half8*)&Ks[key * LP + c * 8] =
            *(const half8*)(kv + kvbase + (long)key * KV_N + c * 8);
    }
#pragma unroll
    for (int it = 0; it < 2; ++it) {
        const int id = it * 256 + tid;
        const int key = id >> 3, c = id & 7;
        const half8 v = *(const half8*)(kv + kvbase + INNER + (long)key * KV_N + c * 8);
#pragma unroll
        for (int j = 0; j < 8; ++j)
            Vt[(c * 8 + j) * LP + key] = v[j];
    }
    __syncthreads();

    const long q0 = ((long)(b * T_TXT + s * 256 + w * 64)) * INNER + h * DIM_HEAD;
    half8 qf[4][2];
#pragma unroll
    for (int tm = 0; tm < 4; ++tm)
#pragma unroll
        for (int ks = 0; ks < 2; ++ks)
            qf[tm][ks] = *(const half8*)(qg + q0 + (long)(tm * 16 + c15) * INNER + ks * 32 + g * 8);

    f32x4 acc[4][4] = {};
#pragma unroll
    for (int tn = 0; tn < 4; ++tn) {
        const half8 kf0 = *(const half8*)&Ks[(tn * 16 + c15) * LP + g * 8];
        const half8 kf1 = *(const half8*)&Ks[(tn * 16 + c15) * LP + 32 + g * 8];
#pragma unroll
        for (int tm = 0; tm < 4; ++tm) {
            acc[tm][tn] = __builtin_amdgcn_mfma_f32_16x16x32_f16(qf[tm][0], kf0, acc[tm][tn], 0, 0, 0);
            acc[tm][tn] = __builtin_amdgcn_mfma_f32_16x16x32_f16(qf[tm][1], kf1, acc[tm][tn], 0, 0, 0);
        }
    }

    constexpr float sc = 0.125f;
    _Float16* Pw = Ps + w * (64 * LP);
#pragma unroll
    for (int tm = 0; tm < 4; ++tm)
#pragma unroll
        for (int r = 0; r < 4; ++r) {
            float m = fmaxf(fmaxf(acc[tm][0][r], acc[tm][1][r]),
                            fmaxf(acc[tm][2][r], acc[tm][3][r]));
#pragma unroll
            for (int off = 1; off < 16; off <<= 1) m = fmaxf(m, __shfl_xor(m, off));
            float e0 = __expf((acc[tm][0][r] - m) * sc);
            float e1 = __expf((acc[tm][1][r] - m) * sc);
            float e2 = __expf((acc[tm][2][r] - m) * sc);
            float e3 = __expf((acc[tm][3][r] - m) * sc);
            float sum = e0 + e1 + e2 + e3;
#pragma unroll
            for (int off = 1; off < 16; off <<= 1) sum += __shfl_xor(sum, off);
            const float inv = 1.0f / sum;
            const int row = tm * 16 + g * 4 + r;
            Pw[row * LP +  0 + c15] = (_Float16)(e0 * inv);
            Pw[row * LP + 16 + c15] = (_Float16)(e1 * inv);
            Pw[row * LP + 32 + c15] = (_Float16)(e2 * inv);
            Pw[row * LP + 48 + c15] = (_Float16)(e3 * inv);
        }
    __syncthreads();

    f32x4 o[4][4] = {};
#pragma unroll
    for (int ks = 0; ks < 2; ++ks) {
        half8 pf[4];
#pragma unroll
        for (int tm = 0; tm < 4; ++tm)
            pf[tm] = *(const half8*)&Pw[(tm * 16 + c15) * LP + ks * 32 + g * 8];
#pragma unroll
        for (int tn = 0; tn < 4; ++tn) {
            const half8 vf = *(const half8*)&Vt[(tn * 16 + c15) * LP + ks * 32 + g * 8];
#pragma unroll
            for (int tm = 0; tm < 4; ++tm)
                o[tm][tn] = __builtin_amdgcn_mfma_f32_16x16x32_f16(pf[tm], vf, o[tm][tn], 0, 0, 0);
        }
    }

    const long obase = ((long)(b * T_TXT + s * 256 + w * 64)) * INNER + h * DIM_HEAD;
#pragma unroll
    for (int tm = 0; tm < 4; ++tm)
#pragma unroll
        for (int tn = 0; tn < 4; ++tn)
#pragma unroll
            for (int r = 0; r < 4; ++r)
                attn[obase + (long)(tm * 16 + g * 4 + r) * INNER + tn * 16 + c15] =
                    (_Float16)o[tm][tn][r];
}

// ---------------------------------------------------------------------------
extern "C" void kernel_launch(void* const* d_in, const int* in_sizes, int n_in,
                              void* d_out, int out_size, void* d_ws, size_t ws_size,
                              hipStream_t stream)
{
    (void)in_sizes; (void)n_in; (void)out_size; (void)ws_size;
    const float* x      = (const float*)d_in[0];
    const float* media  = (const float*)d_in[1];
    const float* norm_w = (const float*)d_in[2];
    const float* norm_b = (const float*)d_in[3];
    const float* Wq     = (const float*)d_in[4];
    const float* Wkv    = (const float*)d_in[5];
    const float* Wo     = (const float*)d_in[6];

    char* ws = (char*)d_ws;
    char* outc = (char*)d_out;
    // ws (60 MB):
    _Float16* xn     = (_Float16*)ws;                    // [0,32) MB
    _Float16* attnb  = (_Float16*)ws;                    // [0,16) MB alias (xn dead after QKV)
    _Float16* qbuf   = (_Float16*)(ws + (32ull << 20));  // [32,48) MB
    _Float16* kvb    = (_Float16*)(ws + (48ull << 20));  // [48,56) MB
    _Float16* woT    = (_Float16*)(ws + (56ull << 20));  // [56,60) MB
    // d_out as scratch (dead before the final O-GEMM, which overwrites all 64 MB):
    _Float16* wqT    = (_Float16*)outc;                  // [0,4) MB
    _Float16* wkvT   = (_Float16*)(outc + (4ull << 20)); // [4,8) MB
    _Float16* mediaf = (_Float16*)(outc + (8ull << 20)); // [8,12) MB
    float* out = (float*)d_out;

    // 1) fused prepass: LN + media->f16 + WkvT + WqT + WoT (one dispatch)
    prepass<<<dim3(10752), dim3(256), 0, stream>>>(
        x, norm_w, norm_b, xn, media, mediaf, Wkv, wkvT, Wq, wqT, Wo, woT);

    // 2) fused KV + Q GEMM (384 WGs, KV first)
    gemm_qkv<<<dim3(384), dim3(512), 0, stream>>>(xn, wqT, qbuf, mediaf, wkvT, kvb);

    // 3) masked cross-attention
    attn_mfma<<<dim3(T_IMG, HEADS, B_SZ), dim3(256), 0, stream>>>(qbuf, kvb, attnb);

    // 4) out = attn @ Wo  (8192x2048, K=1024; 256 WGs -> 8-phase 256^2)
    gemm256<false><<<dim3(DIM / 256, (B_SZ * T_TXT) / 256), dim3(512), 0, stream>>>(
        attnb, woT, out, B_SZ * T_TXT, DIM, INNER);
}